// Round 9
// baseline (194.799 us; speedup 1.0000x reference)
//
#include <hip/hip_runtime.h>

#define B_ 8
#define CI 64
#define CO 64
#define H_ 256
#define W_ 256
#define EPS_ 1e-5f

#define SELU_SCALE 1.0507009873554805f
#define SELU_SA    1.7580993408473766f

typedef __attribute__((ext_vector_type(8))) short short8;
typedef __attribute__((ext_vector_type(4))) float f32x4;
typedef unsigned int u32;

__device__ __forceinline__ unsigned short f2bf(float f) {
    unsigned int u = __float_as_uint(f);
    u = (u + 0x7fffu + ((u >> 16) & 1u)) >> 16;
    return (unsigned short)u;
}
__device__ __forceinline__ float bf2f(unsigned short h) {
    return __uint_as_float(((unsigned)h) << 16);
}
__device__ __forceinline__ float selu_f(float u) {
    return (u > 0.f) ? SELU_SCALE * u : SELU_SA * (__expf(u) - 1.f);
}
__device__ __forceinline__ void gload_lds16(const void* g, void* l) {
    __builtin_amdgcn_global_load_lds(
        (const __attribute__((address_space(1))) u32*)g,
        (__attribute__((address_space(3))) u32*)l, 16, 0, 0);
}

// ===========================================================================
// Weight prepass (unchanged from R8).
// ===========================================================================
__global__ __launch_bounds__(256) void prepass_weights(
    const float* __restrict__ w_int,
    const float* __restrict__ w_bl, const float* __restrict__ w_br,
    const float* __restrict__ w_tl, const float* __restrict__ w_tr,
    const float* __restrict__ w_bot, const float* __restrict__ w_top,
    const float* __restrict__ w_left, const float* __restrict__ w_right,
    unsigned short* __restrict__ wpre, float* __restrict__ wedge)
{
    const int blk = blockIdx.x, t = threadIdx.x;
    if (blk < 72) {
        const int wid = blk / 9, pos = blk % 9;
        const float* src = (wid == 0) ? w_bl : (wid == 1) ? w_br
                         : (wid == 2) ? w_tl : (wid == 3) ? w_tr
                         : (wid == 4) ? w_bot : (wid == 5) ? w_top
                         : (wid == 6) ? w_left : w_right;
        float* dst = wedge + (size_t)blk * 4096;
        for (int k = 0; k < 16; ++k) {
            const int lin = k * 256 + t;        // [ci4][co][j]
            const int c4  = lin >> 8;
            const int co  = (lin >> 2) & 63;
            const int j   = lin & 3;
            const int ci  = c4 * 4 + j;
            dst[lin] = src[(co * 64 + ci) * 9 + pos];
        }
    } else {
        const int pos = blk - 72;
        for (int k = 0; k < 16; ++k) {
            const int lin = k * 256 + t;
            const int co = lin >> 6, cip = lin & 63;
            const int ci = cip ^ ((co & 7) << 3);
            wpre[pos * 4096 + lin] = f2bf(w_int[(co * 64 + ci) * 9 + pos]);
        }
    }
}

// ===========================================================================
// Prepass: x fp32 NCHW -> bf16 NHWC swizzled: xpre[b][row][col][ci^((col&7)<<3)]
// ===========================================================================
__global__ __launch_bounds__(256) void prepass_x(
    const float* __restrict__ x, unsigned short* __restrict__ xpre)
{
    __shared__ unsigned short ls[256 * 72];
    const int row = blockIdx.x, b = blockIdx.y;
    const int t = threadIdx.x;
    const int colq = t >> 2;
    const float* xb = x + ((size_t)(b * 64) * 256 + row) * 256;

    for (int sp = 0; sp < 4; ++sp) {
        const int cibase = sp * 16 + (t & 3) * 4;
        float4 v[4];
#pragma unroll
        for (int e = 0; e < 4; ++e)
            v[e] = *(const float4*)(xb + (size_t)(cibase + e) * 65536 + colq * 4);
#pragma unroll
        for (int jj = 0; jj < 4; ++jj) {
            const int col = colq * 4 + jj;
            const int sw  = (col & 7) << 3;
            ushort4 pk;
            pk.x = f2bf((&v[0].x)[jj]);
            pk.y = f2bf((&v[1].x)[jj]);
            pk.z = f2bf((&v[2].x)[jj]);
            pk.w = f2bf((&v[3].x)[jj]);
            *(ushort4*)&ls[col * 72 + (cibase ^ sw)] = pk;
        }
    }
    __syncthreads();
    unsigned short* xp = xpre + ((size_t)(b * 256 + row)) * 256 * 64;
    for (int q = 0; q < 8; ++q) {
        const int lin = q * 256 + t;
        const int col = lin >> 3, k = lin & 7;
        *(uint4*)(xp + col * 64 + k * 8) = *(const uint4*)&ls[col * 72 + k * 8];
    }
}

// ===========================================================================
// MFMA conv + fused masked group-stats partials.
// v5: block = 8 rows x 64 cols (grid 4x32x8); wave = 1 row x 64 cols x 64 co
// with 4x4 accumulator. LDS reads/MFMA drop 0.75 -> 0.5 (A reused 4x).
// xs[10][80][64] = 102.4 KB; 1 block/CU.
// ===========================================================================
__global__ __launch_bounds__(512, 2) void conv_mfma(
    const unsigned short* __restrict__ xpre, const unsigned short* __restrict__ wpre,
    const float* __restrict__ bias, unsigned short* __restrict__ ybf,
    float* __restrict__ part)
{
    __shared__ unsigned short xs[10 * 80 * 64];   // 102400 B
    __shared__ unsigned short wl2[2][4096];       // 16384 B
    __shared__ float sred[8][16][2];              // 1024 B
    const int t = threadIdx.x, w = t >> 6, lane = t & 63;
    const int b = blockIdx.z, r0 = blockIdx.y * 8, c0 = blockIdx.x * 64;

    // ---- stage x tile: 100 wave-chunks of 1 KB (rows r0-1..r0+8, slots 0..79)
    for (int L = w; L < 100; L += 8) {
        const int j = L / 10, i = L % 10;
        int rr = r0 - 1 + j; rr = rr < 0 ? 0 : (rr > 255 ? 255 : rr);
        int col = c0 - 8 + i * 8 + (lane >> 3);
        col = col < 0 ? 0 : (col > 255 ? 255 : col);
        const char* src = (const char*)xpre +
            ((size_t)((b * 256 + rr) * 256 + col)) * 128 + (lane & 7) * 16;
        gload_lds16(src, (char*)xs + j * 10240 + i * 1024);
    }
    // ---- stage weights for pos 0 (per-lane src)
    gload_lds16((const char*)wpre + w * 1024 + lane * 16,
                (char*)wl2[0] + w * 1024);

    const int l15 = lane & 15, lg = lane >> 4;
    const int sw15 = (l15 & 7) << 3;

    // ---- hoisted loop-invariant offsets
    int jb[3];
#pragma unroll
    for (int kr = 0; kr < 3; ++kr) jb[kr] = (w + kr) * 10240;
    int offb[3][4][2];
#pragma unroll
    for (int kc = 0; kc < 3; ++kc)
#pragma unroll
        for (int n = 0; n < 4; ++n) {
            const int s = n * 16 + l15 + kc + 7;   // slot 7..72
#pragma unroll
            for (int ks = 0; ks < 2; ++ks) {
                const int cib = ks * 32 + lg * 8;
                offb[kc][n][ks] = s * 128 + ((cib ^ ((s & 7) << 3)) << 1);
            }
        }
    int afo[2][4];
#pragma unroll
    for (int ks = 0; ks < 2; ++ks)
#pragma unroll
        for (int m = 0; m < 4; ++m) {
            const int cib = ks * 32 + lg * 8;
            afo[ks][m] = (m * 16 + l15) * 128 + ((cib ^ sw15) << 1);
        }

    f32x4 acc[4][4];
#pragma unroll
    for (int m = 0; m < 4; ++m)
#pragma unroll
        for (int n = 0; n < 4; ++n)
            acc[m][n] = (f32x4){0.f, 0.f, 0.f, 0.f};

    __syncthreads();

    // ---- K loop: 9 positions x 2 ks-steps; weights double-buffered
#pragma unroll
    for (int pos = 0; pos < 9; ++pos) {
        const int cur = pos & 1;
        if (pos < 8)
            gload_lds16((const char*)wpre + (pos + 1) * 8192 + w * 1024 + lane * 16,
                        (char*)wl2[cur ^ 1] + w * 1024);
        const int kr = pos / 3, kc = pos % 3;
        const char* wbuf = (const char*)wl2[cur];
#pragma unroll
        for (int ks = 0; ks < 2; ++ks) {
            short8 bf[4], af[4];
#pragma unroll
            for (int n = 0; n < 4; ++n)
                bf[n] = *(const short8*)((const char*)xs + jb[kr] + offb[kc][n][ks]);
#pragma unroll
            for (int m = 0; m < 4; ++m)
                af[m] = *(const short8*)(wbuf + afo[ks][m]);
#pragma unroll
            for (int m = 0; m < 4; ++m)
#pragma unroll
                for (int n = 0; n < 4; ++n)
                    acc[m][n] = __builtin_amdgcn_mfma_f32_16x16x32_bf16(
                        af[m], bf[n], acc[m][n], 0, 0, 0);
        }
        __syncthreads();
    }

    // ---- epilogue: bias, bf16 store, masked group partial sums
    const int r = r0 + w;
    const bool rmask = (r != 0) && (r != 255);
    float s4[4] = {0.f, 0.f, 0.f, 0.f}, q4[4] = {0.f, 0.f, 0.f, 0.f};
#pragma unroll
    for (int m = 0; m < 4; ++m)
#pragma unroll
        for (int n = 0; n < 4; ++n) {
            const int c = c0 + n * 16 + l15;
            const bool pmask = rmask && (c != 0) && (c != 255);
#pragma unroll
            for (int reg = 0; reg < 4; ++reg) {
                const int co = m * 16 + lg * 4 + reg;
                const float v = acc[m][n][reg] + bias[co];
                ybf[(((size_t)b * 64 + co) * 256 + r) * 256 + c] = f2bf(v);
                if (pmask) { s4[m] += v; q4[m] += v * v; }
            }
        }
#pragma unroll
    for (int off = 1; off < 16; off <<= 1)
#pragma unroll
        for (int m = 0; m < 4; ++m) {
            s4[m] += __shfl_xor(s4[m], off);
            q4[m] += __shfl_xor(q4[m], off);
        }
    if (l15 == 0) {
#pragma unroll
        for (int m = 0; m < 4; ++m) {
            sred[w][m * 4 + lg][0] = s4[m];
            sred[w][m * 4 + lg][1] = q4[m];
        }
    }
    __syncthreads();
    if (t < 32) {
        const int g = t & 15, sel = t >> 4;
        float v = 0.f;
#pragma unroll
        for (int ww = 0; ww < 8; ++ww) v += sred[ww][g][sel];
        const int slot = blockIdx.y * 4 + blockIdx.x;     // 0..127
        part[((size_t)(b * 512 + slot) * 16 + g) * 2 + sel] = v;
    }
}

// ===========================================================================
// Border pixels + their stats partials (slots 128..383). bf16 out.
// ===========================================================================
__global__ __launch_bounds__(256) void conv_edge2(
    const unsigned short* __restrict__ xpre, const float* __restrict__ wedge,
    const float* __restrict__ bias, unsigned short* __restrict__ ybf,
    float* __restrict__ part)
{
    __shared__ float xl[4][9][64];    // 9216 B
    __shared__ float ered[4][16][2];  // 512 B
    const int b = blockIdx.x, edge = blockIdx.y, seg = blockIdx.z;
    const int t = threadIdx.x, p = t >> 6, lane = t & 63;

    for (int unit = t; unit < 288; unit += 256) {
        const int chunk = unit >> 3, sub = unit & 7;
        const int pp = chunk / 9, rem = chunk % 9, kr = rem / 3, kc = rem % 3;
        int e = seg * 4 + pp;
        if (edge >= 2 && e > 253) e = 253;
        int row, colb;
        if (edge == 0)      { row = 253 + kr; colb = (e == 0) ? 0 : ((e == 255) ? 253 : (e - 1)); }
        else if (edge == 1) { row = kr;       colb = (e == 0) ? 0 : ((e == 255) ? 253 : (e - 1)); }
        else if (edge == 2) { row = e + kr;   colb = 0; }
        else                { row = e + kr;   colb = 253; }
        const int col = colb + kc;
        const uint4 v = *(const uint4*)(xpre +
            ((size_t)((b * 256 + row) * 256 + col)) * 64 + sub * 8);
        const int ci0 = (sub ^ (col & 7)) * 8;
        float* dst = &xl[pp][kr * 3 + kc][ci0];
        const unsigned short* hv = (const unsigned short*)&v;
#pragma unroll
        for (int j = 0; j < 8; ++j) dst[j] = bf2f(hv[j]);
    }
    __syncthreads();

    int e = seg * 4 + p;
    const bool active = (edge < 2) || (e <= 253);
    if (edge >= 2 && e > 253) e = 253;
    int wid, r_out, c_out;
    if (edge == 0)      { wid = (e == 0) ? 0 : ((e == 255) ? 1 : 4); r_out = 0;   c_out = e; }
    else if (edge == 1) { wid = (e == 0) ? 2 : ((e == 255) ? 3 : 5); r_out = 255; c_out = e; }
    else if (edge == 2) { wid = 6; r_out = e + 1; c_out = 0; }
    else                { wid = 7; r_out = e + 1; c_out = 255; }

    const int co = lane;
    float acc = 0.f;
    const float* wbase = wedge + (size_t)wid * 36864;
#pragma unroll
    for (int pos = 0; pos < 9; ++pos) {
        const float* wp = wbase + pos * 4096 + lane * 4;
        const float* xp = &xl[p][pos][0];
#pragma unroll
        for (int c4 = 0; c4 < 16; ++c4) {
            const float4 wv = *(const float4*)(wp + c4 * 256);
            const float4 xv = *(const float4*)(xp + c4 * 4);
            acc = fmaf(wv.x, xv.x, acc); acc = fmaf(wv.y, xv.y, acc);
            acc = fmaf(wv.z, xv.z, acc); acc = fmaf(wv.w, xv.w, acc);
        }
    }
    const float v = acc + bias[co];
    if (active) ybf[(((size_t)b * 64 + co) * 256 + r_out) * 256 + c_out] = f2bf(v);
    float s = active ? v : 0.f, q = active ? v * v : 0.f;
    s += __shfl_xor(s, 1); q += __shfl_xor(q, 1);
    s += __shfl_xor(s, 2); q += __shfl_xor(q, 2);
    if ((lane & 3) == 0) { ered[p][co >> 2][0] = s; ered[p][co >> 2][1] = q; }
    __syncthreads();
    if (t < 32) {
        const int g = t & 15, sel = t >> 4;
        const float r = ered[0][g][sel] + ered[1][g][sel] +
                        ered[2][g][sel] + ered[3][g][sel];
        const int slot = 128 + (edge * 64 + seg);          // 128..383
        part[((size_t)(b * 512 + slot) * 16 + g) * 2 + sel] = r;
    }
}

// ===========================================================================
// Reduce 384 partial slots -> mean/rstd per (b, group).
// ===========================================================================
__global__ __launch_bounds__(256) void stats_reduce(
    const float* __restrict__ part, float* __restrict__ mv)
{
    __shared__ float sred[16][16][2];
    const int b = blockIdx.x, t = threadIdx.x;
    const int g = t & 15, chunk = t >> 4;
    float s = 0.f, q = 0.f;
    for (int k = 0; k < 24; ++k) {
        const int slot = chunk * 24 + k;                   // 0..383
        const size_t base = ((size_t)(b * 512 + slot) * 16 + g) * 2;
        s += part[base]; q += part[base + 1];
    }
    sred[chunk][g][0] = s; sred[chunk][g][1] = q;
    __syncthreads();
    if (t < 16) {
        float S = 0.f, Q = 0.f;
#pragma unroll
        for (int c = 0; c < 16; ++c) { S += sred[c][t][0]; Q += sred[c][t][1]; }
        const float inv_n = 1.0f / (4.0f * 65536.0f);
        const float mean = S * inv_n;
        const float var  = Q * inv_n - mean * mean;
        mv[(b * 16 + t) * 2]     = mean;
        mv[(b * 16 + t) * 2 + 1] = rsqrtf(var + EPS_);
    }
}

// ===========================================================================
// GroupNorm + SELU: read bf16 ybf, write fp32 out. 8 elems/thread.
// ===========================================================================
__global__ __launch_bounds__(256) void norm_bf(
    const unsigned short* __restrict__ ybf, float* __restrict__ out,
    const float* __restrict__ mv,
    const float* __restrict__ gamma, const float* __restrict__ beta)
{
    const size_t tt = (size_t)blockIdx.x * 256 + threadIdx.x;  // 8-elem unit
    const size_t e = tt * 8;
    const int b  = (int)(e >> 22);
    const int ch = (int)((e >> 16) & 63);
    const int g  = ch >> 2;
    const float mean = mv[(b * 16 + g) * 2];
    const float rstd = mv[(b * 16 + g) * 2 + 1];
    const float ga = gamma[ch] * rstd;
    const float be = beta[ch] - mean * ga;

    const uint4 v = *(const uint4*)(ybf + e);
    float f[8];
    f[0] = __uint_as_float(v.x << 16); f[1] = __uint_as_float(v.x & 0xffff0000u);
    f[2] = __uint_as_float(v.y << 16); f[3] = __uint_as_float(v.y & 0xffff0000u);
    f[4] = __uint_as_float(v.z << 16); f[5] = __uint_as_float(v.z & 0xffff0000u);
    f[6] = __uint_as_float(v.w << 16); f[7] = __uint_as_float(v.w & 0xffff0000u);
    float4 o0, o1;
    o0.x = selu_f(f[0] * ga + be); o0.y = selu_f(f[1] * ga + be);
    o0.z = selu_f(f[2] * ga + be); o0.w = selu_f(f[3] * ga + be);
    o1.x = selu_f(f[4] * ga + be); o1.y = selu_f(f[5] * ga + be);
    o1.z = selu_f(f[6] * ga + be); o1.w = selu_f(f[7] * ga + be);
    *(float4*)(out + e)     = o0;
    *(float4*)(out + e + 4) = o1;
}

// ===========================================================================
// Fallback path (round-1 proven kernels) for small ws.
// ===========================================================================
__global__ __launch_bounds__(256) void conv_main(
    const float* __restrict__ x, const float* __restrict__ w,
    const float* __restrict__ bias, float* __restrict__ y)
{
    const int c = threadIdx.x;
    const int r = blockIdx.x;
    const int b = blockIdx.y;
    const int rr = (r == 0) ? (H_ - 3) : ((r == H_ - 1) ? 0 : (r - 1));
    const int cc = min(max(c - 1, 0), W_ - 3);
    float acc[CO];
#pragma unroll
    for (int co = 0; co < CO; ++co) acc[co] = 0.f;
    const float* xb = x + (size_t)b * CI * H_ * W_;
    for (int ci = 0; ci < CI; ++ci) {
        const float* xp = xb + ((size_t)ci * H_ + rr) * W_ + cc;
        float xv[9];
#pragma unroll
        for (int kr = 0; kr < 3; ++kr)
#pragma unroll
            for (int kc = 0; kc < 3; ++kc)
                xv[kr * 3 + kc] = xp[kr * W_ + kc];
        const float* wci = w + ci * 9;
#pragma unroll
        for (int co = 0; co < CO; ++co) {
            const float* wp = wci + co * (CI * 9);
            float a = acc[co];
#pragma unroll
            for (int k = 0; k < 9; ++k) a = fmaf(xv[k], wp[k], a);
            acc[co] = a;
        }
    }
#pragma unroll
    for (int co = 0; co < CO; ++co)
        y[(((size_t)b * CO + co) * H_ + r) * W_ + c] = acc[co] + bias[co];
}

__global__ __launch_bounds__(256) void conv_edge(
    const float* __restrict__ x,
    const float* __restrict__ w_bot, const float* __restrict__ w_top,
    const float* __restrict__ w_left, const float* __restrict__ w_right,
    const float* __restrict__ bias, float* __restrict__ y)
{
    const int b     = blockIdx.x;
    const int edge  = blockIdx.y;
    const int seg   = blockIdx.z;
    const int el    = threadIdx.x & 63;
    const int chunk = threadIdx.x >> 6;
    const int e     = seg * 64 + el;
    const bool active = (e < 254);
    const int ec    = active ? e : 253;
    const float* w = (edge == 0) ? w_bot : (edge == 1) ? w_top
                   : (edge == 2) ? w_left : w_right;
    int r_out, c_out, rr, cc;
    if (edge == 0)      { r_out = 0;      c_out = 1 + ec; rr = H_ - 3; cc = ec; }
    else if (edge == 1) { r_out = H_ - 1; c_out = 1 + ec; rr = 0;      cc = ec; }
    else if (edge == 2) { r_out = 1 + ec; c_out = 0;      rr = ec;     cc = 0; }
    else                { r_out = 1 + ec; c_out = W_ - 1; rr = ec;     cc = W_ - 3; }
    float acc[CO];
#pragma unroll
    for (int co = 0; co < CO; ++co) acc[co] = 0.f;
    const float* xb = x + (size_t)b * CI * H_ * W_;
    const int ci0 = chunk * 16;
    for (int ci = ci0; ci < ci0 + 16; ++ci) {
        const float* xp = xb + ((size_t)ci * H_ + rr) * W_ + cc;
        float xv[9];
#pragma unroll
        for (int kr = 0; kr < 3; ++kr)
#pragma unroll
            for (int kc = 0; kc < 3; ++kc)
                xv[kr * 3 + kc] = xp[kr * W_ + kc];
#pragma unroll
        for (int co = 0; co < CO; ++co) {
            const float* wp = w + co * (CI * 9) + ci * 9;
            float a = acc[co];
#pragma unroll
            for (int k = 0; k < 9; ++k) a = fmaf(xv[k], wp[k], a);
            acc[co] = a;
        }
    }
    __shared__ float lds[64][65];
    for (int s = 0; s < 4; ++s) {
        if (chunk == s) {
            if (s == 0) {
#pragma unroll
                for (int co = 0; co < CO; ++co) lds[el][co] = acc[co];
            } else {
#pragma unroll
                for (int co = 0; co < CO; ++co) lds[el][co] += acc[co];
            }
        }
        __syncthreads();
    }
    if (chunk == 0 && active) {
#pragma unroll
        for (int co = 0; co < CO; ++co)
            y[(((size_t)b * CO + co) * H_ + r_out) * W_ + c_out] = lds[el][co] + bias[co];
    }
}

__global__ __launch_bounds__(256) void conv_corner(
    const float* __restrict__ x,
    const float* __restrict__ w_bl, const float* __restrict__ w_br,
    const float* __restrict__ w_tl, const float* __restrict__ w_tr,
    const float* __restrict__ bias, float* __restrict__ y)
{
    const int b      = blockIdx.x;
    const int corner = threadIdx.x >> 6;
    const int co     = threadIdx.x & 63;
    const float* w = (corner == 0) ? w_bl : (corner == 1) ? w_br
                   : (corner == 2) ? w_tl : w_tr;
    const int rr    = (corner < 2) ? (H_ - 3) : 0;
    const int cc    = (corner & 1) ? (W_ - 3) : 0;
    const int r_out = (corner < 2) ? 0 : (H_ - 1);
    const int c_out = (corner & 1) ? (W_ - 1) : 0;
    const float* xb = x + (size_t)b * CI * H_ * W_;
    float a = 0.f;
    for (int ci = 0; ci < CI; ++ci) {
        const float* xp = xb + ((size_t)ci * H_ + rr) * W_ + cc;
        const float* wp = w + ((size_t)co * CI + ci) * 9;
#pragma unroll
        for (int kr = 0; kr < 3; ++kr)
#pragma unroll
            for (int kc = 0; kc < 3; ++kc)
                a = fmaf(xp[kr * W_ + kc], wp[kr * 3 + kc], a);
    }
    y[(((size_t)b * CO + co) * H_ + r_out) * W_ + c_out] = a + bias[co];
}

__global__ __launch_bounds__(256) void stats_kernel(
    const float* __restrict__ y, float* __restrict__ ws)
{
    const int bid   = blockIdx.x;
    const int chunk = bid & 3;
    const int g     = (bid >> 2) & 15;
    const int b     = bid >> 6;
    const float* p  = y + ((size_t)(b * 64 + g * 4 + chunk)) * (H_ * W_);
    float s = 0.f, q = 0.f;
    for (int i = threadIdx.x; i < (H_ * W_ / 4); i += 256) {
        float4 v = reinterpret_cast<const float4*>(p)[i];
        s += v.x + v.y + v.z + v.w;
        q += v.x * v.x + v.y * v.y + v.z * v.z + v.w * v.w;
    }
#pragma unroll
    for (int off = 32; off; off >>= 1) {
        s += __shfl_down(s, off);
        q += __shfl_down(q, off);
    }
    __shared__ float red[8];
    const int wid = threadIdx.x >> 6;
    if ((threadIdx.x & 63) == 0) { red[wid * 2] = s; red[wid * 2 + 1] = q; }
    __syncthreads();
    if (threadIdx.x == 0) {
        ws[bid * 2]     = red[0] + red[2] + red[4] + red[6];
        ws[bid * 2 + 1] = red[1] + red[3] + red[5] + red[7];
    }
}

__global__ __launch_bounds__(256) void norm_stats(
    float* __restrict__ y, const float* __restrict__ st,
    const float* __restrict__ gamma, const float* __restrict__ beta)
{
    const size_t t = (size_t)blockIdx.x * 256 + threadIdx.x;
    const size_t e = t * 4;
    const int b  = (int)(e >> 22);
    const int ch = (int)((e >> 16) & 63);
    const int g  = ch >> 2;
    const int sb = ((b * 16 + g) * 4) * 2;
    const float S = st[sb] + st[sb + 2] + st[sb + 4] + st[sb + 6];
    const float Q = st[sb + 1] + st[sb + 3] + st[sb + 5] + st[sb + 7];
    const float inv_n = 1.0f / (4.0f * H_ * W_);
    const float mean  = S * inv_n;
    const float var   = Q * inv_n - mean * mean;
    const float rstd  = rsqrtf(var + EPS_);
    const float ga = gamma[ch] * rstd;
    const float be = beta[ch] - mean * ga;
    float4 v = reinterpret_cast<float4*>(y)[t];
    float u;
    u = v.x * ga + be; v.x = selu_f(u);
    u = v.y * ga + be; v.y = selu_f(u);
    u = v.z * ga + be; v.z = selu_f(u);
    u = v.w * ga + be; v.w = selu_f(u);
    reinterpret_cast<float4*>(y)[t] = v;
}

extern "C" void kernel_launch(void* const* d_in, const int* in_sizes, int n_in,
                              void* d_out, int out_size, void* d_ws, size_t ws_size,
                              hipStream_t stream) {
    const float* x       = (const float*)d_in[0];
    const float* w_int   = (const float*)d_in[1];
    const float* w_tl    = (const float*)d_in[2];
    const float* w_tr    = (const float*)d_in[3];
    const float* w_bl    = (const float*)d_in[4];
    const float* w_br    = (const float*)d_in[5];
    const float* w_top   = (const float*)d_in[6];
    const float* w_bot   = (const float*)d_in[7];
    const float* w_left  = (const float*)d_in[8];
    const float* w_right = (const float*)d_in[9];
    const float* bias    = (const float*)d_in[10];
    const float* gamma   = (const float*)d_in[11];
    const float* beta    = (const float*)d_in[12];

    float* out = (float*)d_out;

    const size_t XPRE  = 67108864ull;                  // bf16 x NHWC
    const size_t YBF   = 67108864ull;                  // bf16 y NCHW
    const size_t WPRE  = 73728ull;                     // bf16 w_int
    const size_t WEDGE = 1179648ull;                   // fp32 [8][9][16][64][4]
    const size_t PART  = 524288ull;                    // [8][512][16][2] f32
    const size_t MV    = 1024ull;                      // [8][16][2] f32
    const size_t NEED  = XPRE + YBF + WPRE + WEDGE + PART + MV;

    if (ws_size >= NEED) {
        unsigned short* xpre = (unsigned short*)d_ws;
        unsigned short* ybf  = (unsigned short*)((char*)d_ws + XPRE);
        unsigned short* wpre = (unsigned short*)((char*)d_ws + XPRE + YBF);
        float* wedge = (float*)((char*)d_ws + XPRE + YBF + WPRE);
        float* part  = (float*)((char*)d_ws + XPRE + YBF + WPRE + WEDGE);
        float* mv    = (float*)((char*)d_ws + XPRE + YBF + WPRE + WEDGE + PART);

        prepass_weights<<<dim3(81), 256, 0, stream>>>(
            w_int, w_bl, w_br, w_tl, w_tr, w_bot, w_top, w_left, w_right, wpre, wedge);
        prepass_x<<<dim3(256, 8), 256, 0, stream>>>(x, xpre);
        conv_mfma<<<dim3(4, 32, 8), 512, 0, stream>>>(xpre, wpre, bias, ybf, part);
        conv_edge2<<<dim3(8, 4, 64), 256, 0, stream>>>(xpre, wedge, bias, ybf, part);
        stats_reduce<<<dim3(8), 256, 0, stream>>>(part, mv);
        norm_bf<<<dim3(16384), 256, 0, stream>>>(ybf, out, mv, gamma, beta);
    } else {
        float* stats = (float*)d_ws;
        conv_main<<<dim3(H_, B_), 256, 0, stream>>>(x, w_int, bias, out);
        conv_edge<<<dim3(B_, 4, 4), 256, 0, stream>>>(x, w_bot, w_top, w_left, w_right, bias, out);
        conv_corner<<<dim3(B_), 256, 0, stream>>>(x, w_bl, w_br, w_tl, w_tr, bias, out);
        stats_kernel<<<dim3(512), 256, 0, stream>>>(out, stats);
        norm_stats<<<dim3(32768), 256, 0, stream>>>(out, stats, gamma, beta);
    }
}

// Round 10
// 181.286 us; speedup vs baseline: 1.0745x; 1.0745x over previous
//
#include <hip/hip_runtime.h>

#define B_ 8
#define CI 64
#define CO 64
#define H_ 256
#define W_ 256
#define EPS_ 1e-5f

#define SELU_SCALE 1.0507009873554805f
#define SELU_SA    1.7580993408473766f

typedef __attribute__((ext_vector_type(8))) short short8;
typedef __attribute__((ext_vector_type(4))) float f32x4;
typedef unsigned int u32;

__device__ __forceinline__ unsigned short f2bf(float f) {
    unsigned int u = __float_as_uint(f);
    u = (u + 0x7fffu + ((u >> 16) & 1u)) >> 16;
    return (unsigned short)u;
}
__device__ __forceinline__ float bf2f(unsigned short h) {
    return __uint_as_float(((unsigned)h) << 16);
}
__device__ __forceinline__ float selu_f(float u) {
    return (u > 0.f) ? SELU_SCALE * u : SELU_SA * (__expf(u) - 1.f);
}
__device__ __forceinline__ void gload_lds16(const void* g, void* l) {
    __builtin_amdgcn_global_load_lds(
        (const __attribute__((address_space(1))) u32*)g,
        (__attribute__((address_space(3))) u32*)l, 16, 0, 0);
}

// ===========================================================================
// Weight prepass (R8).
// ===========================================================================
__global__ __launch_bounds__(256) void prepass_weights(
    const float* __restrict__ w_int,
    const float* __restrict__ w_bl, const float* __restrict__ w_br,
    const float* __restrict__ w_tl, const float* __restrict__ w_tr,
    const float* __restrict__ w_bot, const float* __restrict__ w_top,
    const float* __restrict__ w_left, const float* __restrict__ w_right,
    unsigned short* __restrict__ wpre, float* __restrict__ wedge)
{
    const int blk = blockIdx.x, t = threadIdx.x;
    if (blk < 72) {
        const int wid = blk / 9, pos = blk % 9;
        const float* src = (wid == 0) ? w_bl : (wid == 1) ? w_br
                         : (wid == 2) ? w_tl : (wid == 3) ? w_tr
                         : (wid == 4) ? w_bot : (wid == 5) ? w_top
                         : (wid == 6) ? w_left : w_right;
        float* dst = wedge + (size_t)blk * 4096;
        for (int k = 0; k < 16; ++k) {
            const int lin = k * 256 + t;        // [ci4][co][j]
            const int c4  = lin >> 8;
            const int co  = (lin >> 2) & 63;
            const int j   = lin & 3;
            const int ci  = c4 * 4 + j;
            dst[lin] = src[(co * 64 + ci) * 9 + pos];
        }
    } else {
        const int pos = blk - 72;
        for (int k = 0; k < 16; ++k) {
            const int lin = k * 256 + t;
            const int co = lin >> 6, cip = lin & 63;
            const int ci = cip ^ ((co & 7) << 3);
            wpre[pos * 4096 + lin] = f2bf(w_int[(co * 64 + ci) * 9 + pos]);
        }
    }
}

// ===========================================================================
// Prepass: x fp32 NCHW -> bf16 NHWC swizzled: xpre[b][row][col][ci^((col&7)<<3)]
// ===========================================================================
__global__ __launch_bounds__(256) void prepass_x(
    const float* __restrict__ x, unsigned short* __restrict__ xpre)
{
    __shared__ unsigned short ls[256 * 72];
    const int row = blockIdx.x, b = blockIdx.y;
    const int t = threadIdx.x;
    const int colq = t >> 2;
    const float* xb = x + ((size_t)(b * 64) * 256 + row) * 256;

    for (int sp = 0; sp < 4; ++sp) {
        const int cibase = sp * 16 + (t & 3) * 4;
        float4 v[4];
#pragma unroll
        for (int e = 0; e < 4; ++e)
            v[e] = *(const float4*)(xb + (size_t)(cibase + e) * 65536 + colq * 4);
#pragma unroll
        for (int jj = 0; jj < 4; ++jj) {
            const int col = colq * 4 + jj;
            const int sw  = (col & 7) << 3;
            ushort4 pk;
            pk.x = f2bf((&v[0].x)[jj]);
            pk.y = f2bf((&v[1].x)[jj]);
            pk.z = f2bf((&v[2].x)[jj]);
            pk.w = f2bf((&v[3].x)[jj]);
            *(ushort4*)&ls[col * 72 + (cibase ^ sw)] = pk;
        }
    }
    __syncthreads();
    unsigned short* xp = xpre + ((size_t)(b * 256 + row)) * 256 * 64;
    for (int q = 0; q < 8; ++q) {
        const int lin = q * 256 + t;
        const int col = lin >> 3, k = lin & 7;
        *(uint4*)(xp + col * 64 + k * 8) = *(const uint4*)&ls[col * 72 + k * 8];
    }
}

// ===========================================================================
// MFMA conv + fused masked group-stats partials.
// v6 = R8 geometry (8 rows x 32 cols, 62.5 KB LDS, 2 blocks/CU) + T5
// s_setprio around each MFMA cluster (9-phase schedule with 2 co-resident
// blocks -> wave role diversity, the regime where setprio pays).
// ===========================================================================
__global__ __launch_bounds__(512, 4) void conv_mfma(
    const unsigned short* __restrict__ xpre, const unsigned short* __restrict__ wpre,
    const float* __restrict__ bias, unsigned short* __restrict__ ybf,
    float* __restrict__ part)
{
    __shared__ unsigned short xs[10 * 48 * 64];   // 61440 B
    __shared__ unsigned short wl2[2][4096];       // 16384 B
    __shared__ float sred[8][16][2];              // 1024 B
    const int t = threadIdx.x, w = t >> 6, lane = t & 63;
    const int b = blockIdx.z, r0 = blockIdx.y * 8, c0 = blockIdx.x * 32;

    // ---- stage weights for pos 0 first (latency hides under x staging)
    gload_lds16((const char*)wpre + w * 1024 + lane * 16,
                (char*)wl2[0] + w * 1024);
    // ---- stage x tile via async global->LDS (dest = uniform base + lane*16)
    for (int L = w; L < 60; L += 8) {
        const int j = L / 6, i = L % 6;
        int rr = r0 - 1 + j; rr = rr < 0 ? 0 : (rr > 255 ? 255 : rr);
        int col = c0 - 8 + i * 8 + (lane >> 3);
        col = col < 0 ? 0 : (col > 255 ? 255 : col);
        const char* src = (const char*)xpre +
            ((size_t)((b * 256 + rr) * 256 + col)) * 128 + (lane & 7) * 16;
        gload_lds16(src, (char*)xs + j * 6144 + i * 1024);
    }

    const int l15 = lane & 15, lg = lane >> 4;
    const int sw15 = (l15 & 7) << 3;

    // ---- hoisted loop-invariant offsets
    int jb[3];
#pragma unroll
    for (int kr = 0; kr < 3; ++kr) jb[kr] = (w + kr) * 6144;
    int offb[3][2][2];
#pragma unroll
    for (int kc = 0; kc < 3; ++kc)
#pragma unroll
        for (int n = 0; n < 2; ++n) {
            const int s = n * 16 + l15 + kc + 7;
#pragma unroll
            for (int ks = 0; ks < 2; ++ks) {
                const int cib = ks * 32 + lg * 8;
                offb[kc][n][ks] = s * 128 + ((cib ^ ((s & 7) << 3)) << 1);
            }
        }
    int afo[2][4];
#pragma unroll
    for (int ks = 0; ks < 2; ++ks)
#pragma unroll
        for (int m = 0; m < 4; ++m) {
            const int cib = ks * 32 + lg * 8;
            afo[ks][m] = (m * 16 + l15) * 128 + ((cib ^ sw15) << 1);
        }

    f32x4 acc[4][2];
#pragma unroll
    for (int m = 0; m < 4; ++m)
#pragma unroll
        for (int n = 0; n < 2; ++n)
            acc[m][n] = (f32x4){0.f, 0.f, 0.f, 0.f};

    __syncthreads();

    // ---- K loop over 9 positions, 2 ks-steps each; weights double-buffered
#pragma unroll
    for (int pos = 0; pos < 9; ++pos) {
        const int cur = pos & 1;
        if (pos < 8)
            gload_lds16((const char*)wpre + (pos + 1) * 8192 + w * 1024 + lane * 16,
                        (char*)wl2[cur ^ 1] + w * 1024);
        const int kr = pos / 3, kc = pos % 3;
        const char* wbuf = (const char*)wl2[cur];
#pragma unroll
        for (int ks = 0; ks < 2; ++ks) {
            short8 bf[2], af[4];
#pragma unroll
            for (int n = 0; n < 2; ++n)
                bf[n] = *(const short8*)((const char*)xs + jb[kr] + offb[kc][n][ks]);
#pragma unroll
            for (int m = 0; m < 4; ++m)
                af[m] = *(const short8*)(wbuf + afo[ks][m]);
            __builtin_amdgcn_s_setprio(1);
#pragma unroll
            for (int m = 0; m < 4; ++m)
#pragma unroll
                for (int n = 0; n < 2; ++n)
                    acc[m][n] = __builtin_amdgcn_mfma_f32_16x16x32_bf16(
                        af[m], bf[n], acc[m][n], 0, 0, 0);
            __builtin_amdgcn_s_setprio(0);
        }
        __syncthreads();
    }

    // ---- epilogue: bias, bf16 store, masked group partial sums
    const int r = r0 + w;
    const bool rmask = (r != 0) && (r != 255);
    float s4[4] = {0.f, 0.f, 0.f, 0.f}, q4[4] = {0.f, 0.f, 0.f, 0.f};
#pragma unroll
    for (int m = 0; m < 4; ++m)
#pragma unroll
        for (int n = 0; n < 2; ++n) {
            const int c = c0 + n * 16 + l15;
            const bool pmask = rmask && (c != 0) && (c != 255);
#pragma unroll
            for (int reg = 0; reg < 4; ++reg) {
                const int co = m * 16 + lg * 4 + reg;
                const float v = acc[m][n][reg] + bias[co];
                ybf[(((size_t)b * 64 + co) * 256 + r) * 256 + c] = f2bf(v);
                if (pmask) { s4[m] += v; q4[m] += v * v; }
            }
        }
#pragma unroll
    for (int off = 1; off < 16; off <<= 1)
#pragma unroll
        for (int m = 0; m < 4; ++m) {
            s4[m] += __shfl_xor(s4[m], off);
            q4[m] += __shfl_xor(q4[m], off);
        }
    if (l15 == 0) {
#pragma unroll
        for (int m = 0; m < 4; ++m) {
            sred[w][m * 4 + lg][0] = s4[m];
            sred[w][m * 4 + lg][1] = q4[m];
        }
    }
    __syncthreads();
    if (t < 32) {
        const int g = t & 15, sel = t >> 4;
        float v = 0.f;
#pragma unroll
        for (int ww = 0; ww < 8; ++ww) v += sred[ww][g][sel];
        const int slot = blockIdx.y * 8 + blockIdx.x;      // 0..255
        part[((size_t)(b * 512 + slot) * 16 + g) * 2 + sel] = v;
    }
}

// ===========================================================================
// Border pixels (all 4 edges + corners) + their stats partials. bf16 out.
// ===========================================================================
__global__ __launch_bounds__(256) void conv_edge2(
    const unsigned short* __restrict__ xpre, const float* __restrict__ wedge,
    const float* __restrict__ bias, unsigned short* __restrict__ ybf,
    float* __restrict__ part)
{
    __shared__ float xl[4][9][64];    // 9216 B
    __shared__ float ered[4][16][2];  // 512 B
    const int b = blockIdx.x, edge = blockIdx.y, seg = blockIdx.z;
    const int t = threadIdx.x, p = t >> 6, lane = t & 63;

    for (int unit = t; unit < 288; unit += 256) {
        const int chunk = unit >> 3, sub = unit & 7;
        const int pp = chunk / 9, rem = chunk % 9, kr = rem / 3, kc = rem % 3;
        int e = seg * 4 + pp;
        if (edge >= 2 && e > 253) e = 253;
        int row, colb;
        if (edge == 0)      { row = 253 + kr; colb = (e == 0) ? 0 : ((e == 255) ? 253 : (e - 1)); }
        else if (edge == 1) { row = kr;       colb = (e == 0) ? 0 : ((e == 255) ? 253 : (e - 1)); }
        else if (edge == 2) { row = e + kr;   colb = 0; }
        else                { row = e + kr;   colb = 253; }
        const int col = colb + kc;
        const uint4 v = *(const uint4*)(xpre +
            ((size_t)((b * 256 + row) * 256 + col)) * 64 + sub * 8);
        const int ci0 = (sub ^ (col & 7)) * 8;
        float* dst = &xl[pp][kr * 3 + kc][ci0];
        const unsigned short* hv = (const unsigned short*)&v;
#pragma unroll
        for (int j = 0; j < 8; ++j) dst[j] = bf2f(hv[j]);
    }
    __syncthreads();

    int e = seg * 4 + p;
    const bool active = (edge < 2) || (e <= 253);
    if (edge >= 2 && e > 253) e = 253;
    int wid, r_out, c_out;
    if (edge == 0)      { wid = (e == 0) ? 0 : ((e == 255) ? 1 : 4); r_out = 0;   c_out = e; }
    else if (edge == 1) { wid = (e == 0) ? 2 : ((e == 255) ? 3 : 5); r_out = 255; c_out = e; }
    else if (edge == 2) { wid = 6; r_out = e + 1; c_out = 0; }
    else                { wid = 7; r_out = e + 1; c_out = 255; }

    const int co = lane;
    float acc = 0.f;
    const float* wbase = wedge + (size_t)wid * 36864;
#pragma unroll
    for (int pos = 0; pos < 9; ++pos) {
        const float* wp = wbase + pos * 4096 + lane * 4;
        const float* xp = &xl[p][pos][0];
#pragma unroll
        for (int c4 = 0; c4 < 16; ++c4) {
            const float4 wv = *(const float4*)(wp + c4 * 256);
            const float4 xv = *(const float4*)(xp + c4 * 4);
            acc = fmaf(wv.x, xv.x, acc); acc = fmaf(wv.y, xv.y, acc);
            acc = fmaf(wv.z, xv.z, acc); acc = fmaf(wv.w, xv.w, acc);
        }
    }
    const float v = acc + bias[co];
    if (active) ybf[(((size_t)b * 64 + co) * 256 + r_out) * 256 + c_out] = f2bf(v);
    float s = active ? v : 0.f, q = active ? v * v : 0.f;
    s += __shfl_xor(s, 1); q += __shfl_xor(q, 1);
    s += __shfl_xor(s, 2); q += __shfl_xor(q, 2);
    if ((lane & 3) == 0) { ered[p][co >> 2][0] = s; ered[p][co >> 2][1] = q; }
    __syncthreads();
    if (t < 32) {
        const int g = t & 15, sel = t >> 4;
        const float r = ered[0][g][sel] + ered[1][g][sel] +
                        ered[2][g][sel] + ered[3][g][sel];
        const int slot = 256 + (edge * 64 + seg);          // 256..511
        part[((size_t)(b * 512 + slot) * 16 + g) * 2 + sel] = r;
    }
}

// ===========================================================================
// Reduce 512 partial slots -> mean/rstd per (b, group).
// ===========================================================================
__global__ __launch_bounds__(256) void stats_reduce(
    const float* __restrict__ part, float* __restrict__ mv)
{
    __shared__ float sred[16][16][2];
    const int b = blockIdx.x, t = threadIdx.x;
    const int g = t & 15, chunk = t >> 4;
    float s = 0.f, q = 0.f;
    for (int k = 0; k < 32; ++k) {
        const int slot = chunk * 32 + k;
        const size_t base = ((size_t)(b * 512 + slot) * 16 + g) * 2;
        s += part[base]; q += part[base + 1];
    }
    sred[chunk][g][0] = s; sred[chunk][g][1] = q;
    __syncthreads();
    if (t < 16) {
        float S = 0.f, Q = 0.f;
#pragma unroll
        for (int c = 0; c < 16; ++c) { S += sred[c][t][0]; Q += sred[c][t][1]; }
        const float inv_n = 1.0f / (4.0f * 65536.0f);
        const float mean = S * inv_n;
        const float var  = Q * inv_n - mean * mean;
        mv[(b * 16 + t) * 2]     = mean;
        mv[(b * 16 + t) * 2 + 1] = rsqrtf(var + EPS_);
    }
}

// ===========================================================================
// GroupNorm + SELU: read bf16 ybf, write fp32 out. 8 elems/thread.
// ===========================================================================
__global__ __launch_bounds__(256) void norm_bf(
    const unsigned short* __restrict__ ybf, float* __restrict__ out,
    const float* __restrict__ mv,
    const float* __restrict__ gamma, const float* __restrict__ beta)
{
    const size_t tt = (size_t)blockIdx.x * 256 + threadIdx.x;  // 8-elem unit
    const size_t e = tt * 8;
    const int b  = (int)(e >> 22);
    const int ch = (int)((e >> 16) & 63);
    const int g  = ch >> 2;
    const float mean = mv[(b * 16 + g) * 2];
    const float rstd = mv[(b * 16 + g) * 2 + 1];
    const float ga = gamma[ch] * rstd;
    const float be = beta[ch] - mean * ga;

    const uint4 v = *(const uint4*)(ybf + e);
    float f[8];
    f[0] = __uint_as_float(v.x << 16); f[1] = __uint_as_float(v.x & 0xffff0000u);
    f[2] = __uint_as_float(v.y << 16); f[3] = __uint_as_float(v.y & 0xffff0000u);
    f[4] = __uint_as_float(v.z << 16); f[5] = __uint_as_float(v.z & 0xffff0000u);
    f[6] = __uint_as_float(v.w << 16); f[7] = __uint_as_float(v.w & 0xffff0000u);
    float4 o0, o1;
    o0.x = selu_f(f[0] * ga + be); o0.y = selu_f(f[1] * ga + be);
    o0.z = selu_f(f[2] * ga + be); o0.w = selu_f(f[3] * ga + be);
    o1.x = selu_f(f[4] * ga + be); o1.y = selu_f(f[5] * ga + be);
    o1.z = selu_f(f[6] * ga + be); o1.w = selu_f(f[7] * ga + be);
    *(float4*)(out + e)     = o0;
    *(float4*)(out + e + 4) = o1;
}

// ===========================================================================
// Fallback path (round-1 proven kernels) for small ws.
// ===========================================================================
__global__ __launch_bounds__(256) void conv_main(
    const float* __restrict__ x, const float* __restrict__ w,
    const float* __restrict__ bias, float* __restrict__ y)
{
    const int c = threadIdx.x;
    const int r = blockIdx.x;
    const int b = blockIdx.y;
    const int rr = (r == 0) ? (H_ - 3) : ((r == H_ - 1) ? 0 : (r - 1));
    const int cc = min(max(c - 1, 0), W_ - 3);
    float acc[CO];
#pragma unroll
    for (int co = 0; co < CO; ++co) acc[co] = 0.f;
    const float* xb = x + (size_t)b * CI * H_ * W_;
    for (int ci = 0; ci < CI; ++ci) {
        const float* xp = xb + ((size_t)ci * H_ + rr) * W_ + cc;
        float xv[9];
#pragma unroll
        for (int kr = 0; kr < 3; ++kr)
#pragma unroll
            for (int kc = 0; kc < 3; ++kc)
                xv[kr * 3 + kc] = xp[kr * W_ + kc];
        const float* wci = w + ci * 9;
#pragma unroll
        for (int co = 0; co < CO; ++co) {
            const float* wp = wci + co * (CI * 9);
            float a = acc[co];
#pragma unroll
            for (int k = 0; k < 9; ++k) a = fmaf(xv[k], wp[k], a);
            acc[co] = a;
        }
    }
#pragma unroll
    for (int co = 0; co < CO; ++co)
        y[(((size_t)b * CO + co) * H_ + r) * W_ + c] = acc[co] + bias[co];
}

__global__ __launch_bounds__(256) void conv_edge(
    const float* __restrict__ x,
    const float* __restrict__ w_bot, const float* __restrict__ w_top,
    const float* __restrict__ w_left, const float* __restrict__ w_right,
    const float* __restrict__ bias, float* __restrict__ y)
{
    const int b     = blockIdx.x;
    const int edge  = blockIdx.y;
    const int seg   = blockIdx.z;
    const int el    = threadIdx.x & 63;
    const int chunk = threadIdx.x >> 6;
    const int e     = seg * 64 + el;
    const bool active = (e < 254);
    const int ec    = active ? e : 253;
    const float* w = (edge == 0) ? w_bot : (edge == 1) ? w_top
                   : (edge == 2) ? w_left : w_right;
    int r_out, c_out, rr, cc;
    if (edge == 0)      { r_out = 0;      c_out = 1 + ec; rr = H_ - 3; cc = ec; }
    else if (edge == 1) { r_out = H_ - 1; c_out = 1 + ec; rr = 0;      cc = ec; }
    else if (edge == 2) { r_out = 1 + ec; c_out = 0;      rr = ec;     cc = 0; }
    else                { r_out = 1 + ec; c_out = W_ - 1; rr = ec;     cc = W_ - 3; }
    float acc[CO];
#pragma unroll
    for (int co = 0; co < CO; ++co) acc[co] = 0.f;
    const float* xb = x + (size_t)b * CI * H_ * W_;
    const int ci0 = chunk * 16;
    for (int ci = ci0; ci < ci0 + 16; ++ci) {
        const float* xp = xb + ((size_t)ci * H_ + rr) * W_ + cc;
        float xv[9];
#pragma unroll
        for (int kr = 0; kr < 3; ++kr)
#pragma unroll
            for (int kc = 0; kc < 3; ++kc)
                xv[kr * 3 + kc] = xp[kr * W_ + kc];
#pragma unroll
        for (int co = 0; co < CO; ++co) {
            const float* wp = w + co * (CI * 9) + ci * 9;
            float a = acc[co];
#pragma unroll
            for (int k = 0; k < 9; ++k) a = fmaf(xv[k], wp[k], a);
            acc[co] = a;
        }
    }
    __shared__ float lds[64][65];
    for (int s = 0; s < 4; ++s) {
        if (chunk == s) {
            if (s == 0) {
#pragma unroll
                for (int co = 0; co < CO; ++co) lds[el][co] = acc[co];
            } else {
#pragma unroll
                for (int co = 0; co < CO; ++co) lds[el][co] += acc[co];
            }
        }
        __syncthreads();
    }
    if (chunk == 0 && active) {
#pragma unroll
        for (int co = 0; co < CO; ++co)
            y[(((size_t)b * CO + co) * H_ + r_out) * W_ + c_out] = lds[el][co] + bias[co];
    }
}

__global__ __launch_bounds__(256) void conv_corner(
    const float* __restrict__ x,
    const float* __restrict__ w_bl, const float* __restrict__ w_br,
    const float* __restrict__ w_tl, const float* __restrict__ w_tr,
    const float* __restrict__ bias, float* __restrict__ y)
{
    const int b      = blockIdx.x;
    const int corner = threadIdx.x >> 6;
    const int co     = threadIdx.x & 63;
    const float* w = (corner == 0) ? w_bl : (corner == 1) ? w_br
                   : (corner == 2) ? w_tl : w_tr;
    const int rr    = (corner < 2) ? (H_ - 3) : 0;
    const int cc    = (corner & 1) ? (W_ - 3) : 0;
    const int r_out = (corner < 2) ? 0 : (H_ - 1);
    const int c_out = (corner & 1) ? (W_ - 1) : 0;
    const float* xb = x + (size_t)b * CI * H_ * W_;
    float a = 0.f;
    for (int ci = 0; ci < CI; ++ci) {
        const float* xp = xb + ((size_t)ci * H_ + rr) * W_ + cc;
        const float* wp = w + ((size_t)co * CI + ci) * 9;
#pragma unroll
        for (int kr = 0; kr < 3; ++kr)
#pragma unroll
            for (int kc = 0; kc < 3; ++kc)
                a = fmaf(xp[kr * W_ + kc], wp[kr * 3 + kc], a);
    }
    y[(((size_t)b * CO + co) * H_ + r_out) * W_ + c_out] = a + bias[co];
}

__global__ __launch_bounds__(256) void stats_kernel(
    const float* __restrict__ y, float* __restrict__ ws)
{
    const int bid   = blockIdx.x;
    const int chunk = bid & 3;
    const int g     = (bid >> 2) & 15;
    const int b     = bid >> 6;
    const float* p  = y + ((size_t)(b * 64 + g * 4 + chunk)) * (H_ * W_);
    float s = 0.f, q = 0.f;
    for (int i = threadIdx.x; i < (H_ * W_ / 4); i += 256) {
        float4 v = reinterpret_cast<const float4*>(p)[i];
        s += v.x + v.y + v.z + v.w;
        q += v.x * v.x + v.y * v.y + v.z * v.z + v.w * v.w;
    }
#pragma unroll
    for (int off = 32; off; off >>= 1) {
        s += __shfl_down(s, off);
        q += __shfl_down(q, off);
    }
    __shared__ float red[8];
    const int wid = threadIdx.x >> 6;
    if ((threadIdx.x & 63) == 0) { red[wid * 2] = s; red[wid * 2 + 1] = q; }
    __syncthreads();
    if (threadIdx.x == 0) {
        ws[bid * 2]     = red[0] + red[2] + red[4] + red[6];
        ws[bid * 2 + 1] = red[1] + red[3] + red[5] + red[7];
    }
}

__global__ __launch_bounds__(256) void norm_stats(
    float* __restrict__ y, const float* __restrict__ st,
    const float* __restrict__ gamma, const float* __restrict__ beta)
{
    const size_t t = (size_t)blockIdx.x * 256 + threadIdx.x;
    const size_t e = t * 4;
    const int b  = (int)(e >> 22);
    const int ch = (int)((e >> 16) & 63);
    const int g  = ch >> 2;
    const int sb = ((b * 16 + g) * 4) * 2;
    const float S = st[sb] + st[sb + 2] + st[sb + 4] + st[sb + 6];
    const float Q = st[sb + 1] + st[sb + 3] + st[sb + 5] + st[sb + 7];
    const float inv_n = 1.0f / (4.0f * H_ * W_);
    const float mean  = S * inv_n;
    const float var   = Q * inv_n - mean * mean;
    const float rstd  = rsqrtf(var + EPS_);
    const float ga = gamma[ch] * rstd;
    const float be = beta[ch] - mean * ga;
    float4 v = reinterpret_cast<float4*>(y)[t];
    float u;
    u = v.x * ga + be; v.x = selu_f(u);
    u = v.y * ga + be; v.y = selu_f(u);
    u = v.z * ga + be; v.z = selu_f(u);
    u = v.w * ga + be; v.w = selu_f(u);
    reinterpret_cast<float4*>(y)[t] = v;
}

extern "C" void kernel_launch(void* const* d_in, const int* in_sizes, int n_in,
                              void* d_out, int out_size, void* d_ws, size_t ws_size,
                              hipStream_t stream) {
    const float* x       = (const float*)d_in[0];
    const float* w_int   = (const float*)d_in[1];
    const float* w_tl    = (const float*)d_in[2];
    const float* w_tr    = (const float*)d_in[3];
    const float* w_bl    = (const float*)d_in[4];
    const float* w_br    = (const float*)d_in[5];
    const float* w_top   = (const float*)d_in[6];
    const float* w_bot   = (const float*)d_in[7];
    const float* w_left  = (const float*)d_in[8];
    const float* w_right = (const float*)d_in[9];
    const float* bias    = (const float*)d_in[10];
    const float* gamma   = (const float*)d_in[11];
    const float* beta    = (const float*)d_in[12];

    float* out = (float*)d_out;

    const size_t XPRE  = 67108864ull;                  // bf16 x NHWC
    const size_t YBF   = 67108864ull;                  // bf16 y NCHW
    const size_t WPRE  = 73728ull;                     // bf16 w_int
    const size_t WEDGE = 1179648ull;                   // fp32 [8][9][16][64][4]
    const size_t PART  = 524288ull;                    // [8][512][16][2] f32
    const size_t MV    = 1024ull;                      // [8][16][2] f32
    const size_t NEED  = XPRE + YBF + WPRE + WEDGE + PART + MV;

    if (ws_size >= NEED) {
        unsigned short* xpre = (unsigned short*)d_ws;
        unsigned short* ybf  = (unsigned short*)((char*)d_ws + XPRE);
        unsigned short* wpre = (unsigned short*)((char*)d_ws + XPRE + YBF);
        float* wedge = (float*)((char*)d_ws + XPRE + YBF + WPRE);
        float* part  = (float*)((char*)d_ws + XPRE + YBF + WPRE + WEDGE);
        float* mv    = (float*)((char*)d_ws + XPRE + YBF + WPRE + WEDGE + PART);

        prepass_weights<<<dim3(81), 256, 0, stream>>>(
            w_int, w_bl, w_br, w_tl, w_tr, w_bot, w_top, w_left, w_right, wpre, wedge);
        prepass_x<<<dim3(256, 8), 256, 0, stream>>>(x, xpre);
        conv_mfma<<<dim3(8, 32, 8), 512, 0, stream>>>(xpre, wpre, bias, ybf, part);
        conv_edge2<<<dim3(8, 4, 64), 256, 0, stream>>>(xpre, wedge, bias, ybf, part);
        stats_reduce<<<dim3(8), 256, 0, stream>>>(part, mv);
        norm_bf<<<dim3(16384), 256, 0, stream>>>(ybf, out, mv, gamma, beta);
    } else {
        float* stats = (float*)d_ws;
        conv_main<<<dim3(H_, B_), 256, 0, stream>>>(x, w_int, bias, out);
        conv_edge<<<dim3(B_, 4, 4), 256, 0, stream>>>(x, w_bot, w_top, w_left, w_right, bias, out);
        conv_corner<<<dim3(B_), 256, 0, stream>>>(x, w_bl, w_br, w_tl, w_tr, bias, out);
        stats_kernel<<<dim3(512), 256, 0, stream>>>(out, stats);
        norm_stats<<<dim3(32768), 256, 0, stream>>>(out, stats, gamma, beta);
    }
}

// Round 11
// 178.796 us; speedup vs baseline: 1.0895x; 1.0139x over previous
//
#include <hip/hip_runtime.h>

#define B_ 8
#define CI 64
#define CO 64
#define H_ 256
#define W_ 256
#define EPS_ 1e-5f

#define SELU_SCALE 1.0507009873554805f
#define SELU_SA    1.7580993408473766f

typedef __attribute__((ext_vector_type(8))) short short8;
typedef __attribute__((ext_vector_type(4))) float f32x4;
typedef unsigned int u32;

__device__ __forceinline__ unsigned short f2bf(float f) {
    unsigned int u = __float_as_uint(f);
    u = (u + 0x7fffu + ((u >> 16) & 1u)) >> 16;
    return (unsigned short)u;
}
__device__ __forceinline__ float bf2f(unsigned short h) {
    return __uint_as_float(((unsigned)h) << 16);
}
__device__ __forceinline__ float selu_f(float u) {
    return (u > 0.f) ? SELU_SCALE * u : SELU_SA * (__expf(u) - 1.f);
}
__device__ __forceinline__ void gload_lds16(const void* g, void* l) {
    __builtin_amdgcn_global_load_lds(
        (const __attribute__((address_space(1))) u32*)g,
        (__attribute__((address_space(3))) u32*)l, 16, 0, 0);
}

// ===========================================================================
// Weight prepass (R8).
// ===========================================================================
__global__ __launch_bounds__(256) void prepass_weights(
    const float* __restrict__ w_int,
    const float* __restrict__ w_bl, const float* __restrict__ w_br,
    const float* __restrict__ w_tl, const float* __restrict__ w_tr,
    const float* __restrict__ w_bot, const float* __restrict__ w_top,
    const float* __restrict__ w_left, const float* __restrict__ w_right,
    unsigned short* __restrict__ wpre, float* __restrict__ wedge)
{
    const int blk = blockIdx.x, t = threadIdx.x;
    if (blk < 72) {
        const int wid = blk / 9, pos = blk % 9;
        const float* src = (wid == 0) ? w_bl : (wid == 1) ? w_br
                         : (wid == 2) ? w_tl : (wid == 3) ? w_tr
                         : (wid == 4) ? w_bot : (wid == 5) ? w_top
                         : (wid == 6) ? w_left : w_right;
        float* dst = wedge + (size_t)blk * 4096;
        for (int k = 0; k < 16; ++k) {
            const int lin = k * 256 + t;        // [ci4][co][j]
            const int c4  = lin >> 8;
            const int co  = (lin >> 2) & 63;
            const int j   = lin & 3;
            const int ci  = c4 * 4 + j;
            dst[lin] = src[(co * 64 + ci) * 9 + pos];
        }
    } else {
        const int pos = blk - 72;
        for (int k = 0; k < 16; ++k) {
            const int lin = k * 256 + t;
            const int co = lin >> 6, cip = lin & 63;
            const int ci = cip ^ ((co & 7) << 3);
            wpre[pos * 4096 + lin] = f2bf(w_int[(co * 64 + ci) * 9 + pos]);
        }
    }
}

// ===========================================================================
// Prepass: x fp32 NCHW -> bf16 NHWC swizzled: xpre[b][row][col][ci^((col&7)<<3)]
// ===========================================================================
__global__ __launch_bounds__(256) void prepass_x(
    const float* __restrict__ x, unsigned short* __restrict__ xpre)
{
    __shared__ unsigned short ls[256 * 72];
    const int row = blockIdx.x, b = blockIdx.y;
    const int t = threadIdx.x;
    const int colq = t >> 2;
    const float* xb = x + ((size_t)(b * 64) * 256 + row) * 256;

    for (int sp = 0; sp < 4; ++sp) {
        const int cibase = sp * 16 + (t & 3) * 4;
        float4 v[4];
#pragma unroll
        for (int e = 0; e < 4; ++e)
            v[e] = *(const float4*)(xb + (size_t)(cibase + e) * 65536 + colq * 4);
#pragma unroll
        for (int jj = 0; jj < 4; ++jj) {
            const int col = colq * 4 + jj;
            const int sw  = (col & 7) << 3;
            ushort4 pk;
            pk.x = f2bf((&v[0].x)[jj]);
            pk.y = f2bf((&v[1].x)[jj]);
            pk.z = f2bf((&v[2].x)[jj]);
            pk.w = f2bf((&v[3].x)[jj]);
            *(ushort4*)&ls[col * 72 + (cibase ^ sw)] = pk;
        }
    }
    __syncthreads();
    unsigned short* xp = xpre + ((size_t)(b * 256 + row)) * 256 * 64;
    for (int q = 0; q < 8; ++q) {
        const int lin = q * 256 + t;
        const int col = lin >> 3, k = lin & 7;
        *(uint4*)(xp + col * 64 + k * 8) = *(const uint4*)&ls[col * 72 + k * 8];
    }
}

// ===========================================================================
// MFMA conv + fused masked group-stats partials.
// v7: xs shrunk to 40 col-slots (cols c0-2..c0+37; 51.2 KB) and 3-buffer
// weight pipeline with raw s_barrier + COUNTED vmcnt (never 0 mid-loop):
// W_p is issued 2 phases before use, stays in flight across barriers (T4).
// LDS 64.5 KB -> 2 blocks/CU.
// ===========================================================================
__global__ __launch_bounds__(512, 4) void conv_mfma(
    const unsigned short* __restrict__ xpre, const unsigned short* __restrict__ wpre,
    const float* __restrict__ bias, unsigned short* __restrict__ ybf,
    float* __restrict__ part)
{
    __shared__ unsigned short xs[10 * 40 * 64];   // 51200 B
    __shared__ unsigned short wl3[3][4096];       // 12288 B
    __shared__ float sred[8][16][2];              // 1024 B
    const int t = threadIdx.x, w = t >> 6, lane = t & 63;
    const int b = blockIdx.z, r0 = blockIdx.y * 8, c0 = blockIdx.x * 32;

    // ---- stage x tile: 50 chunks of 1 KB (rows r0-1..r0+8, cols c0-2..c0+37)
    for (int L = w; L < 50; L += 8) {
        const int j = L / 5, i = L % 5;
        int rr = r0 - 1 + j; rr = rr < 0 ? 0 : (rr > 255 ? 255 : rr);
        int col = c0 - 2 + i * 8 + (lane >> 3);
        col = col < 0 ? 0 : (col > 255 ? 255 : col);
        const char* src = (const char*)xpre +
            ((size_t)((b * 256 + rr) * 256 + col)) * 128 + (lane & 7) * 16;
        gload_lds16(src, (char*)xs + j * 5120 + i * 1024);
    }
    // ---- stage weights for pos 0 and 1 (per-lane src)
    gload_lds16((const char*)wpre + 0 * 8192 + w * 1024 + lane * 16,
                (char*)wl3[0] + w * 1024);
    gload_lds16((const char*)wpre + 1 * 8192 + w * 1024 + lane * 16,
                (char*)wl3[1] + w * 1024);

    const int l15 = lane & 15, lg = lane >> 4;
    const int sw15 = (l15 & 7) << 3;

    // ---- hoisted loop-invariant offsets
    int jb[3];
#pragma unroll
    for (int kr = 0; kr < 3; ++kr) jb[kr] = (w + kr) * 5120;
    int offb[3][2][2];
#pragma unroll
    for (int kc = 0; kc < 3; ++kc)
#pragma unroll
        for (int n = 0; n < 2; ++n) {
            const int s = n * 16 + l15 + kc + 1;       // slot 1..34
#pragma unroll
            for (int ks = 0; ks < 2; ++ks) {
                const int cib = ks * 32 + lg * 8;
                offb[kc][n][ks] = s * 128 + ((cib ^ (((s + 6) & 7) << 3)) << 1);
            }
        }
    int afo[2][4];
#pragma unroll
    for (int ks = 0; ks < 2; ++ks)
#pragma unroll
        for (int m = 0; m < 4; ++m) {
            const int cib = ks * 32 + lg * 8;
            afo[ks][m] = (m * 16 + l15) * 128 + ((cib ^ sw15) << 1);
        }

    f32x4 acc[4][2];
#pragma unroll
    for (int m = 0; m < 4; ++m)
#pragma unroll
        for (int n = 0; n < 2; ++n)
            acc[m][n] = (f32x4){0.f, 0.f, 0.f, 0.f};

    // ---- K loop: 9 positions; counted-vmcnt pipeline, depth-2 prefetch.
#pragma unroll
    for (int pos = 0; pos < 9; ++pos) {
        // own W_pos chunk complete (only W_{pos+1} may remain in flight)
        if (pos < 8) asm volatile("s_waitcnt vmcnt(1)" ::: "memory");
        else         asm volatile("s_waitcnt vmcnt(0)" ::: "memory");
        __builtin_amdgcn_s_barrier();          // all waves' W_pos chunks done
        __builtin_amdgcn_sched_barrier(0);
        if (pos + 2 <= 8)                      // buf (pos+2)%3 last read at pos-1
            gload_lds16((const char*)wpre + (pos + 2) * 8192 + w * 1024 + lane * 16,
                        (char*)wl3[(pos + 2) % 3] + w * 1024);
        const int kr = pos / 3, kc = pos % 3;
        const char* wbuf = (const char*)wl3[pos % 3];
#pragma unroll
        for (int ks = 0; ks < 2; ++ks) {
            short8 bf[2], af[4];
#pragma unroll
            for (int n = 0; n < 2; ++n)
                bf[n] = *(const short8*)((const char*)xs + jb[kr] + offb[kc][n][ks]);
#pragma unroll
            for (int m = 0; m < 4; ++m)
                af[m] = *(const short8*)(wbuf + afo[ks][m]);
            __builtin_amdgcn_s_setprio(1);
#pragma unroll
            for (int m = 0; m < 4; ++m)
#pragma unroll
                for (int n = 0; n < 2; ++n)
                    acc[m][n] = __builtin_amdgcn_mfma_f32_16x16x32_bf16(
                        af[m], bf[n], acc[m][n], 0, 0, 0);
            __builtin_amdgcn_s_setprio(0);
        }
    }

    // ---- epilogue: bias, bf16 store, masked group partial sums
    const int r = r0 + w;
    const bool rmask = (r != 0) && (r != 255);
    float s4[4] = {0.f, 0.f, 0.f, 0.f}, q4[4] = {0.f, 0.f, 0.f, 0.f};
#pragma unroll
    for (int m = 0; m < 4; ++m)
#pragma unroll
        for (int n = 0; n < 2; ++n) {
            const int c = c0 + n * 16 + l15;
            const bool pmask = rmask && (c != 0) && (c != 255);
#pragma unroll
            for (int reg = 0; reg < 4; ++reg) {
                const int co = m * 16 + lg * 4 + reg;
                const float v = acc[m][n][reg] + bias[co];
                ybf[(((size_t)b * 64 + co) * 256 + r) * 256 + c] = f2bf(v);
                if (pmask) { s4[m] += v; q4[m] += v * v; }
            }
        }
#pragma unroll
    for (int off = 1; off < 16; off <<= 1)
#pragma unroll
        for (int m = 0; m < 4; ++m) {
            s4[m] += __shfl_xor(s4[m], off);
            q4[m] += __shfl_xor(q4[m], off);
        }
    if (l15 == 0) {
#pragma unroll
        for (int m = 0; m < 4; ++m) {
            sred[w][m * 4 + lg][0] = s4[m];
            sred[w][m * 4 + lg][1] = q4[m];
        }
    }
    __syncthreads();
    if (t < 32) {
        const int g = t & 15, sel = t >> 4;
        float v = 0.f;
#pragma unroll
        for (int ww = 0; ww < 8; ++ww) v += sred[ww][g][sel];
        const int slot = blockIdx.y * 8 + blockIdx.x;      // 0..255
        part[((size_t)(b * 512 + slot) * 16 + g) * 2 + sel] = v;
    }
}

// ===========================================================================
// Border pixels (all 4 edges + corners) + their stats partials. bf16 out.
// ===========================================================================
__global__ __launch_bounds__(256) void conv_edge2(
    const unsigned short* __restrict__ xpre, const float* __restrict__ wedge,
    const float* __restrict__ bias, unsigned short* __restrict__ ybf,
    float* __restrict__ part)
{
    __shared__ float xl[4][9][64];    // 9216 B
    __shared__ float ered[4][16][2];  // 512 B
    const int b = blockIdx.x, edge = blockIdx.y, seg = blockIdx.z;
    const int t = threadIdx.x, p = t >> 6, lane = t & 63;

    for (int unit = t; unit < 288; unit += 256) {
        const int chunk = unit >> 3, sub = unit & 7;
        const int pp = chunk / 9, rem = chunk % 9, kr = rem / 3, kc = rem % 3;
        int e = seg * 4 + pp;
        if (edge >= 2 && e > 253) e = 253;
        int row, colb;
        if (edge == 0)      { row = 253 + kr; colb = (e == 0) ? 0 : ((e == 255) ? 253 : (e - 1)); }
        else if (edge == 1) { row = kr;       colb = (e == 0) ? 0 : ((e == 255) ? 253 : (e - 1)); }
        else if (edge == 2) { row = e + kr;   colb = 0; }
        else                { row = e + kr;   colb = 253; }
        const int col = colb + kc;
        const uint4 v = *(const uint4*)(xpre +
            ((size_t)((b * 256 + row) * 256 + col)) * 64 + sub * 8);
        const int ci0 = (sub ^ (col & 7)) * 8;
        float* dst = &xl[pp][kr * 3 + kc][ci0];
        const unsigned short* hv = (const unsigned short*)&v;
#pragma unroll
        for (int j = 0; j < 8; ++j) dst[j] = bf2f(hv[j]);
    }
    __syncthreads();

    int e = seg * 4 + p;
    const bool active = (edge < 2) || (e <= 253);
    if (edge >= 2 && e > 253) e = 253;
    int wid, r_out, c_out;
    if (edge == 0)      { wid = (e == 0) ? 0 : ((e == 255) ? 1 : 4); r_out = 0;   c_out = e; }
    else if (edge == 1) { wid = (e == 0) ? 2 : ((e == 255) ? 3 : 5); r_out = 255; c_out = e; }
    else if (edge == 2) { wid = 6; r_out = e + 1; c_out = 0; }
    else                { wid = 7; r_out = e + 1; c_out = 255; }

    const int co = lane;
    float acc = 0.f;
    const float* wbase = wedge + (size_t)wid * 36864;
#pragma unroll
    for (int pos = 0; pos < 9; ++pos) {
        const float* wp = wbase + pos * 4096 + lane * 4;
        const float* xp = &xl[p][pos][0];
#pragma unroll
        for (int c4 = 0; c4 < 16; ++c4) {
            const float4 wv = *(const float4*)(wp + c4 * 256);
            const float4 xv = *(const float4*)(xp + c4 * 4);
            acc = fmaf(wv.x, xv.x, acc); acc = fmaf(wv.y, xv.y, acc);
            acc = fmaf(wv.z, xv.z, acc); acc = fmaf(wv.w, xv.w, acc);
        }
    }
    const float v = acc + bias[co];
    if (active) ybf[(((size_t)b * 64 + co) * 256 + r_out) * 256 + c_out] = f2bf(v);
    float s = active ? v : 0.f, q = active ? v * v : 0.f;
    s += __shfl_xor(s, 1); q += __shfl_xor(q, 1);
    s += __shfl_xor(s, 2); q += __shfl_xor(q, 2);
    if ((lane & 3) == 0) { ered[p][co >> 2][0] = s; ered[p][co >> 2][1] = q; }
    __syncthreads();
    if (t < 32) {
        const int g = t & 15, sel = t >> 4;
        const float r = ered[0][g][sel] + ered[1][g][sel] +
                        ered[2][g][sel] + ered[3][g][sel];
        const int slot = 256 + (edge * 64 + seg);          // 256..511
        part[((size_t)(b * 512 + slot) * 16 + g) * 2 + sel] = r;
    }
}

// ===========================================================================
// Reduce 512 partial slots -> mean/rstd per (b, group).
// ===========================================================================
__global__ __launch_bounds__(256) void stats_reduce(
    const float* __restrict__ part, float* __restrict__ mv)
{
    __shared__ float sred[16][16][2];
    const int b = blockIdx.x, t = threadIdx.x;
    const int g = t & 15, chunk = t >> 4;
    float s = 0.f, q = 0.f;
    for (int k = 0; k < 32; ++k) {
        const int slot = chunk * 32 + k;
        const size_t base = ((size_t)(b * 512 + slot) * 16 + g) * 2;
        s += part[base]; q += part[base + 1];
    }
    sred[chunk][g][0] = s; sred[chunk][g][1] = q;
    __syncthreads();
    if (t < 16) {
        float S = 0.f, Q = 0.f;
#pragma unroll
        for (int c = 0; c < 16; ++c) { S += sred[c][t][0]; Q += sred[c][t][1]; }
        const float inv_n = 1.0f / (4.0f * 65536.0f);
        const float mean = S * inv_n;
        const float var  = Q * inv_n - mean * mean;
        mv[(b * 16 + t) * 2]     = mean;
        mv[(b * 16 + t) * 2 + 1] = rsqrtf(var + EPS_);
    }
}

// ===========================================================================
// GroupNorm + SELU: read bf16 ybf, write fp32 out. 8 elems/thread.
// ===========================================================================
__global__ __launch_bounds__(256) void norm_bf(
    const unsigned short* __restrict__ ybf, float* __restrict__ out,
    const float* __restrict__ mv,
    const float* __restrict__ gamma, const float* __restrict__ beta)
{
    const size_t tt = (size_t)blockIdx.x * 256 + threadIdx.x;  // 8-elem unit
    const size_t e = tt * 8;
    const int b  = (int)(e >> 22);
    const int ch = (int)((e >> 16) & 63);
    const int g  = ch >> 2;
    const float mean = mv[(b * 16 + g) * 2];
    const float rstd = mv[(b * 16 + g) * 2 + 1];
    const float ga = gamma[ch] * rstd;
    const float be = beta[ch] - mean * ga;

    const uint4 v = *(const uint4*)(ybf + e);
    float f[8];
    f[0] = __uint_as_float(v.x << 16); f[1] = __uint_as_float(v.x & 0xffff0000u);
    f[2] = __uint_as_float(v.y << 16); f[3] = __uint_as_float(v.y & 0xffff0000u);
    f[4] = __uint_as_float(v.z << 16); f[5] = __uint_as_float(v.z & 0xffff0000u);
    f[6] = __uint_as_float(v.w << 16); f[7] = __uint_as_float(v.w & 0xffff0000u);
    float4 o0, o1;
    o0.x = selu_f(f[0] * ga + be); o0.y = selu_f(f[1] * ga + be);
    o0.z = selu_f(f[2] * ga + be); o0.w = selu_f(f[3] * ga + be);
    o1.x = selu_f(f[4] * ga + be); o1.y = selu_f(f[5] * ga + be);
    o1.z = selu_f(f[6] * ga + be); o1.w = selu_f(f[7] * ga + be);
    *(float4*)(out + e)     = o0;
    *(float4*)(out + e + 4) = o1;
}

// ===========================================================================
// Fallback path (round-1 proven kernels) for small ws.
// ===========================================================================
__global__ __launch_bounds__(256) void conv_main(
    const float* __restrict__ x, const float* __restrict__ w,
    const float* __restrict__ bias, float* __restrict__ y)
{
    const int c = threadIdx.x;
    const int r = blockIdx.x;
    const int b = blockIdx.y;
    const int rr = (r == 0) ? (H_ - 3) : ((r == H_ - 1) ? 0 : (r - 1));
    const int cc = min(max(c - 1, 0), W_ - 3);
    float acc[CO];
#pragma unroll
    for (int co = 0; co < CO; ++co) acc[co] = 0.f;
    const float* xb = x + (size_t)b * CI * H_ * W_;
    for (int ci = 0; ci < CI; ++ci) {
        const float* xp = xb + ((size_t)ci * H_ + rr) * W_ + cc;
        float xv[9];
#pragma unroll
        for (int kr = 0; kr < 3; ++kr)
#pragma unroll
            for (int kc = 0; kc < 3; ++kc)
                xv[kr * 3 + kc] = xp[kr * W_ + kc];
        const float* wci = w + ci * 9;
#pragma unroll
        for (int co = 0; co < CO; ++co) {
            const float* wp = wci + co * (CI * 9);
            float a = acc[co];
#pragma unroll
            for (int k = 0; k < 9; ++k) a = fmaf(xv[k], wp[k], a);
            acc[co] = a;
        }
    }
#pragma unroll
    for (int co = 0; co < CO; ++co)
        y[(((size_t)b * CO + co) * H_ + r) * W_ + c] = acc[co] + bias[co];
}

__global__ __launch_bounds__(256) void conv_edge(
    const float* __restrict__ x,
    const float* __restrict__ w_bot, const float* __restrict__ w_top,
    const float* __restrict__ w_left, const float* __restrict__ w_right,
    const float* __restrict__ bias, float* __restrict__ y)
{
    const int b     = blockIdx.x;
    const int edge  = blockIdx.y;
    const int seg   = blockIdx.z;
    const int el    = threadIdx.x & 63;
    const int chunk = threadIdx.x >> 6;
    const int e     = seg * 64 + el;
    const bool active = (e < 254);
    const int ec    = active ? e : 253;
    const float* w = (edge == 0) ? w_bot : (edge == 1) ? w_top
                   : (edge == 2) ? w_left : w_right;
    int r_out, c_out, rr, cc;
    if (edge == 0)      { r_out = 0;      c_out = 1 + ec; rr = H_ - 3; cc = ec; }
    else if (edge == 1) { r_out = H_ - 1; c_out = 1 + ec; rr = 0;      cc = ec; }
    else if (edge == 2) { r_out = 1 + ec; c_out = 0;      rr = ec;     cc = 0; }
    else                { r_out = 1 + ec; c_out = W_ - 1; rr = ec;     cc = W_ - 3; }
    float acc[CO];
#pragma unroll
    for (int co = 0; co < CO; ++co) acc[co] = 0.f;
    const float* xb = x + (size_t)b * CI * H_ * W_;
    const int ci0 = chunk * 16;
    for (int ci = ci0; ci < ci0 + 16; ++ci) {
        const float* xp = xb + ((size_t)ci * H_ + rr) * W_ + cc;
        float xv[9];
#pragma unroll
        for (int kr = 0; kr < 3; ++kr)
#pragma unroll
            for (int kc = 0; kc < 3; ++kc)
                xv[kr * 3 + kc] = xp[kr * W_ + kc];
#pragma unroll
        for (int co = 0; co < CO; ++co) {
            const float* wp = w + co * (CI * 9) + ci * 9;
            float a = acc[co];
#pragma unroll
            for (int k = 0; k < 9; ++k) a = fmaf(xv[k], wp[k], a);
            acc[co] = a;
        }
    }
    __shared__ float lds[64][65];
    for (int s = 0; s < 4; ++s) {
        if (chunk == s) {
            if (s == 0) {
#pragma unroll
                for (int co = 0; co < CO; ++co) lds[el][co] = acc[co];
            } else {
#pragma unroll
                for (int co = 0; co < CO; ++co) lds[el][co] += acc[co];
            }
        }
        __syncthreads();
    }
    if (chunk == 0 && active) {
#pragma unroll
        for (int co = 0; co < CO; ++co)
            y[(((size_t)b * CO + co) * H_ + r_out) * W_ + c_out] = lds[el][co] + bias[co];
    }
}

__global__ __launch_bounds__(256) void conv_corner(
    const float* __restrict__ x,
    const float* __restrict__ w_bl, const float* __restrict__ w_br,
    const float* __restrict__ w_tl, const float* __restrict__ w_tr,
    const float* __restrict__ bias, float* __restrict__ y)
{
    const int b      = blockIdx.x;
    const int corner = threadIdx.x >> 6;
    const int co     = threadIdx.x & 63;
    const float* w = (corner == 0) ? w_bl : (corner == 1) ? w_br
                   : (corner == 2) ? w_tl : w_tr;
    const int rr    = (corner < 2) ? (H_ - 3) : 0;
    const int cc    = (corner & 1) ? (W_ - 3) : 0;
    const int r_out = (corner < 2) ? 0 : (H_ - 1);
    const int c_out = (corner & 1) ? (W_ - 1) : 0;
    const float* xb = x + (size_t)b * CI * H_ * W_;
    float a = 0.f;
    for (int ci = 0; ci < CI; ++ci) {
        const float* xp = xb + ((size_t)ci * H_ + rr) * W_ + cc;
        const float* wp = w + ((size_t)co * CI + ci) * 9;
#pragma unroll
        for (int kr = 0; kr < 3; ++kr)
#pragma unroll
            for (int kc = 0; kc < 3; ++kc)
                a = fmaf(xp[kr * W_ + kc], wp[kr * 3 + kc], a);
    }
    y[(((size_t)b * CO + co) * H_ + r_out) * W_ + c_out] = a + bias[co];
}

__global__ __launch_bounds__(256) void stats_kernel(
    const float* __restrict__ y, float* __restrict__ ws)
{
    const int bid   = blockIdx.x;
    const int chunk = bid & 3;
    const int g     = (bid >> 2) & 15;
    const int b     = bid >> 6;
    const float* p  = y + ((size_t)(b * 64 + g * 4 + chunk)) * (H_ * W_);
    float s = 0.f, q = 0.f;
    for (int i = threadIdx.x; i < (H_ * W_ / 4); i += 256) {
        float4 v = reinterpret_cast<const float4*>(p)[i];
        s += v.x + v.y + v.z + v.w;
        q += v.x * v.x + v.y * v.y + v.z * v.z + v.w * v.w;
    }
#pragma unroll
    for (int off = 32; off; off >>= 1) {
        s += __shfl_down(s, off);
        q += __shfl_down(q, off);
    }
    __shared__ float red[8];
    const int wid = threadIdx.x >> 6;
    if ((threadIdx.x & 63) == 0) { red[wid * 2] = s; red[wid * 2 + 1] = q; }
    __syncthreads();
    if (threadIdx.x == 0) {
        ws[bid * 2]     = red[0] + red[2] + red[4] + red[6];
        ws[bid * 2 + 1] = red[1] + red[3] + red[5] + red[7];
    }
}

__global__ __launch_bounds__(256) void norm_stats(
    float* __restrict__ y, const float* __restrict__ st,
    const float* __restrict__ gamma, const float* __restrict__ beta)
{
    const size_t t = (size_t)blockIdx.x * 256 + threadIdx.x;
    const size_t e = t * 4;
    const int b  = (int)(e >> 22);
    const int ch = (int)((e >> 16) & 63);
    const int g  = ch >> 2;
    const int sb = ((b * 16 + g) * 4) * 2;
    const float S = st[sb] + st[sb + 2] + st[sb + 4] + st[sb + 6];
    const float Q = st[sb + 1] + st[sb + 3] + st[sb + 5] + st[sb + 7];
    const float inv_n = 1.0f / (4.0f * H_ * W_);
    const float mean  = S * inv_n;
    const float var   = Q * inv_n - mean * mean;
    const float rstd  = rsqrtf(var + EPS_);
    const float ga = gamma[ch] * rstd;
    const float be = beta[ch] - mean * ga;
    float4 v = reinterpret_cast<float4*>(y)[t];
    float u;
    u = v.x * ga + be; v.x = selu_f(u);
    u = v.y * ga + be; v.y = selu_f(u);
    u = v.z * ga + be; v.z = selu_f(u);
    u = v.w * ga + be; v.w = selu_f(u);
    reinterpret_cast<float4*>(y)[t] = v;
}

extern "C" void kernel_launch(void* const* d_in, const int* in_sizes, int n_in,
                              void* d_out, int out_size, void* d_ws, size_t ws_size,
                              hipStream_t stream) {
    const float* x       = (const float*)d_in[0];
    const float* w_int   = (const float*)d_in[1];
    const float* w_tl    = (const float*)d_in[2];
    const float* w_tr    = (const float*)d_in[3];
    const float* w_bl    = (const float*)d_in[4];
    const float* w_br    = (const float*)d_in[5];
    const float* w_top   = (const float*)d_in[6];
    const float* w_bot   = (const float*)d_in[7];
    const float* w_left  = (const float*)d_in[8];
    const float* w_right = (const float*)d_in[9];
    const float* bias    = (const float*)d_in[10];
    const float* gamma   = (const float*)d_in[11];
    const float* beta    = (const float*)d_in[12];

    float* out = (float*)d_out;

    const size_t XPRE  = 67108864ull;                  // bf16 x NHWC
    const size_t YBF   = 67108864ull;                  // bf16 y NCHW
    const size_t WPRE  = 73728ull;                     // bf16 w_int
    const size_t WEDGE = 1179648ull;                   // fp32 [8][9][16][64][4]
    const size_t PART  = 524288ull;                    // [8][512][16][2] f32
    const size_t MV    = 1024ull;                      // [8][16][2] f32
    const size_t NEED  = XPRE + YBF + WPRE + WEDGE + PART + MV;

    if (ws_size >= NEED) {
        unsigned short* xpre = (unsigned short*)d_ws;
        unsigned short* ybf  = (unsigned short*)((char*)d_ws + XPRE);
        unsigned short* wpre = (unsigned short*)((char*)d_ws + XPRE + YBF);
        float* wedge = (float*)((char*)d_ws + XPRE + YBF + WPRE);
        float* part  = (float*)((char*)d_ws + XPRE + YBF + WPRE + WEDGE);
        float* mv    = (float*)((char*)d_ws + XPRE + YBF + WPRE + WEDGE + PART);

        prepass_weights<<<dim3(81), 256, 0, stream>>>(
            w_int, w_bl, w_br, w_tl, w_tr, w_bot, w_top, w_left, w_right, wpre, wedge);
        prepass_x<<<dim3(256, 8), 256, 0, stream>>>(x, xpre);
        conv_mfma<<<dim3(8, 32, 8), 512, 0, stream>>>(xpre, wpre, bias, ybf, part);
        conv_edge2<<<dim3(8, 4, 64), 256, 0, stream>>>(xpre, wedge, bias, ybf, part);
        stats_reduce<<<dim3(8), 256, 0, stream>>>(part, mv);
        norm_bf<<<dim3(16384), 256, 0, stream>>>(ybf, out, mv, gamma, beta);
    } else {
        float* stats = (float*)d_ws;
        conv_main<<<dim3(H_, B_), 256, 0, stream>>>(x, w_int, bias, out);
        conv_edge<<<dim3(B_, 4, 4), 256, 0, stream>>>(x, w_bot, w_top, w_left, w_right, bias, out);
        conv_corner<<<dim3(B_), 256, 0, stream>>>(x, w_bl, w_br, w_tl, w_tr, bias, out);
        stats_kernel<<<dim3(512), 256, 0, stream>>>(out, stats);
        norm_stats<<<dim3(32768), 256, 0, stream>>>(out, stats, gamma, beta);
    }
}